// Round 8
// baseline (203.757 us; speedup 1.0000x reference)
//
#include <hip/hip_runtime.h>
#include <cstdint>
#include <cstddef>

typedef __attribute__((ext_vector_type(8))) short short8;   // 8 bf16 = 4 VGPRs (MFMA A/B frag)
typedef __attribute__((ext_vector_type(4))) float floatx4;  // MFMA C/D frag

__device__ __forceinline__ float bf2f(unsigned short u) {
  union { unsigned int i; float f; } c; c.i = ((unsigned int)u) << 16; return c.f;
}
__device__ __forceinline__ unsigned short f2bf(float f) {
  union { float f; unsigned int i; } c; c.f = f;
  unsigned int r = c.i + 0x7fffu + ((c.i >> 16) & 1u);  // round-nearest-even
  return (unsigned short)(r >> 16);
}
__device__ __forceinline__ unsigned int fbits(float f) {
  union { float f; unsigned int i; } c; c.f = f; return c.i;
}

// async global->LDS, 16 B per lane; LDS dest = wave-uniform base + lane*16 (m97/m104)
__device__ __forceinline__ void glds16(const unsigned short* g, unsigned short* l) {
  __builtin_amdgcn_global_load_lds((const __attribute__((address_space(1))) void*)g,
                                   (__attribute__((address_space(3))) void*)l, 16, 0, 0);
}

// ---- 32x32 transpose+cvt tile helper (256 threads, 4 rows/thread) ----
__device__ __forceinline__ void tr_tile(const float* __restrict__ in,
                                        unsigned short* __restrict__ out,
                                        int R, int C, int bx, int by, int tid,
                                        unsigned short (*t)[33]) {
  const int cx = tid & 31, rl = tid >> 5;
#pragma unroll
  for (int i = 0; i < 4; ++i)
    t[rl + i * 8][cx] = f2bf(in[(size_t)(by * 32 + rl + i * 8) * C + bx * 32 + cx]);
  __syncthreads();
  const int oc = by * 32 + cx;
#pragma unroll
  for (int i = 0; i < 4; ++i)
    out[(size_t)(bx * 32 + rl + i * 8) * R + oc] = t[cx][rl + i * 8];
}

// ---- fused prep: W_qkv^T (3072 blks) + W_out^T (1024 blks) + x cvt (4096 blks) ----
__global__ __launch_bounds__(256) void k_prep(const float* __restrict__ x,
                                              const float* __restrict__ Wq,
                                              const float* __restrict__ Wo,
                                              unsigned short* __restrict__ x_bf,
                                              unsigned short* __restrict__ WTq,
                                              unsigned short* __restrict__ WTo) {
  __shared__ unsigned short t[32][33];
  const int bid = blockIdx.x, tid = threadIdx.x;
  if (bid < 3072) {
    tr_tile(Wq, WTq, 1024, 3072, bid % 96, bid / 96, tid, t);
  } else if (bid < 4096) {
    int v = bid - 3072;
    tr_tile(Wo, WTo, 1024, 1024, v & 31, v >> 5, tid, t);
  } else {
    int i = (bid - 4096) * 256 + tid;
    float4 v = ((const float4*)x)[i];
    ushort4 o = { f2bf(v.x), f2bf(v.y), f2bf(v.z), f2bf(v.w) };
    ((ushort4*)x_bf)[i] = o;
  }
}

// ---------------- GEMM: C[M][N] = A[M][K] * BT[N][K]^T, bf16 in ----------------
// m97 structure, MT x 128 tile, BK=32, global_load_lds width-16 staging.
template <int MT, bool F32OUT>
__global__ __launch_bounds__(256) void k_gemm_bt(const unsigned short* __restrict__ A,
                                                 const unsigned short* __restrict__ BT,
                                                 void* __restrict__ Cout,
                                                 int M, int N, int K) {
  constexpr int NI = MT / 32;  // per-wave m-frag count (4 or 2)
  __shared__ unsigned short As[MT * 32];
  __shared__ unsigned short Bs[128 * 32];
  const int bm = blockIdx.x * MT, bn = blockIdx.y * 128;
  const int tid = threadIdx.x;
  const int wave = tid >> 6, lane = tid & 63;
  const int wm = (wave & 1) * (MT / 2), wn = (wave >> 1) * 64;
  const int lrow = lane & 15, lgrp = lane >> 4;
  floatx4 acc[NI][4] = {};

  const int lr4 = lane >> 2, lc8 = (lane & 3) * 8;
  const int br0 = wave * 32;
  const unsigned short* Bg0 = BT + (size_t)(bn + br0 + lr4) * K + lc8;
  const unsigned short* Bg1 = BT + (size_t)(bn + br0 + 16 + lr4) * K + lc8;
  unsigned short* lB0 = &Bs[br0 * 32];
  unsigned short* lB1 = &Bs[(br0 + 16) * 32];
  const int ar0 = wave * (MT / 4);
  const unsigned short* Ag0 = A + (size_t)(bm + ar0 + lr4) * K + lc8;
  const unsigned short* Ag1 = A + (size_t)(bm + ar0 + 16 + lr4) * K + lc8;  // MT==128 only
  unsigned short* lA0 = &As[ar0 * 32];
  unsigned short* lA1 = &As[(ar0 + 16) * 32];

  for (int k0 = 0; k0 < K; k0 += 32) {
    glds16(Ag0 + k0, lA0);
    if (MT == 128) glds16(Ag1 + k0, lA1);
    glds16(Bg0 + k0, lB0);
    glds16(Bg1 + k0, lB1);
    __syncthreads();
    short8 a[NI], bfr[4];
#pragma unroll
    for (int i = 0; i < NI; ++i)
      a[i] = *(const short8*)&As[(wm + i * 16 + lrow) * 32 + lgrp * 8];
#pragma unroll
    for (int j = 0; j < 4; ++j)
      bfr[j] = *(const short8*)&Bs[(wn + j * 16 + lrow) * 32 + lgrp * 8];
#pragma unroll
    for (int i = 0; i < NI; ++i)
#pragma unroll
      for (int j = 0; j < 4; ++j)
        acc[i][j] = __builtin_amdgcn_mfma_f32_16x16x32_bf16(a[i], bfr[j], acc[i][j], 0, 0, 0);
    __syncthreads();
  }
#pragma unroll
  for (int i = 0; i < NI; ++i)
#pragma unroll
    for (int j = 0; j < 4; ++j)
#pragma unroll
      for (int r = 0; r < 4; ++r) {
        int m = bm + wm + i * 16 + lgrp * 4 + r;
        int n = bn + wn + j * 16 + lrow;
        if (F32OUT)
          ((float*)Cout)[(size_t)m * N + n] = acc[i][j][r];
        else
          ((unsigned short*)Cout)[(size_t)m * N + n] = f2bf(acc[i][j][r]);
      }
}

// ---- fused LN (4096 blks) + V transpose (4096 blks); both read qkv ----
// LN: q out folded by 0.125*log2(e) so flash uses exp2 directly.
__global__ __launch_bounds__(256) void k_lnv(const unsigned short* __restrict__ qkv,
                                             const float* __restrict__ q_scale,
                                             const float* __restrict__ k_scale,
                                             unsigned short* __restrict__ q_n,
                                             unsigned short* __restrict__ k_n,
                                             unsigned short* __restrict__ VT) {
  const int bid = blockIdx.x, tid = threadIdx.x;
  if (bid < 4096) {
    const int tok = bid;
    const int wave = tid >> 6, lane = tid & 63;
    __shared__ float red[2][4];
    const unsigned short* row = qkv + (size_t)tok * 3072;
#pragma unroll
    for (int seg = 0; seg < 2; ++seg) {
      const unsigned short* p  = row + seg * 1024;
      const float* sc = seg ? k_scale : q_scale;
      unsigned short* outp = (seg ? k_n : q_n) + (size_t)tok * 1024;
      ushort4 u = *(const ushort4*)&p[tid * 4];
      float xv[4] = { bf2f(u.x), bf2f(u.y), bf2f(u.z), bf2f(u.w) };
      float sum = xv[0] + xv[1] + xv[2] + xv[3];
      float sq  = xv[0]*xv[0] + xv[1]*xv[1] + xv[2]*xv[2] + xv[3]*xv[3];
      for (int off = 32; off; off >>= 1) {
        sum += __shfl_down(sum, off, 64);
        sq  += __shfl_down(sq,  off, 64);
      }
      if (lane == 0) { red[0][wave] = sum; red[1][wave] = sq; }
      __syncthreads();
      sum = red[0][0] + red[0][1] + red[0][2] + red[0][3];
      sq  = red[1][0] + red[1][1] + red[1][2] + red[1][3];
      __syncthreads();
      float mean = sum * (1.0f / 1024.0f);
      float var  = sq * (1.0f / 1024.0f) - mean * mean;
      float rstd = rsqrtf(var + 1e-6f);
      if (seg == 0) rstd *= 0.18033688011112042f;  // 0.125 * log2(e)
      float4 su = *(const float4*)&sc[tid * 4];
      ushort4 o;
      o.x = f2bf((xv[0] - mean) * rstd * su.x);
      o.y = f2bf((xv[1] - mean) * rstd * su.y);
      o.z = f2bf((xv[2] - mean) * rstd * su.z);
      o.w = f2bf((xv[3] - mean) * rstd * su.w);
      *(ushort4*)&outp[tid * 4] = o;
    }
  } else {
    // V transpose tile: v-part [b,s,h*64+hd] -> VT[(b*16+h)*64+hd][s]
    __shared__ unsigned short t[32][33];
    const int v = bid - 4096;
    const int bh = v & 31, b = bh >> 4, h = bh & 15;
    const int sy = (v >> 5) & 63, hx = v >> 11;   // s-tile 0..63, hd-tile 0..1
    const int cx = tid & 31, rl = tid >> 5;
#pragma unroll
    for (int i = 0; i < 4; ++i)
      t[rl + i * 8][cx] =
        qkv[(size_t)(b * 2048 + sy * 32 + rl + i * 8) * 3072 + 2048 + h * 64 + hx * 32 + cx];
    __syncthreads();
#pragma unroll
    for (int i = 0; i < 4; ++i)
      VT[((size_t)bh * 64 + hx * 32 + rl + i * 8) * 2048 + sy * 32 + cx] = t[cx][rl + i * 8];
  }
}

// ------------------------------ flash attention ------------------------------
// r8: t-SPLIT ACROSS WAVES. Wave w owns t-sub [t0+32w, t0+32w+32) for ALL 64 q
// (qa regs x4 q-blocks). Per wave per step: 12 ds_read_b128 (was 36 — K rows
// were read 4x redundantly when waves split by q). O is t-partial per wave ->
// one end-of-block LDS tree reduction (reuses dead Ks/Vs region).
// Fixed-max softmax (m=0, validated r4/r5); trunc-packed P; l exact fp32.
// All LDS strides multiples of 8 shorts (16 B) — b128 alignment (r6 lesson).

#define KS_STRIDE 72   // 144 B = 9*16
#define VS_STRIDE 136  // 272 B = 17*16
#define PS_STRIDE 40   // 80 B = 5*16

template <bool MASKED>
__device__ __forceinline__ void attn_step(int t0, int q0, int wave,
    const short8 (&qa)[4][2],
    const unsigned short* Ks, const unsigned short* Vs, unsigned short* Psw,
    floatx4 (&o)[4][4], float (&l)[4], int lrow, int lgrp) {
  const int tw = t0 + wave * 32;
#pragma unroll
  for (int tb = 0; tb < 2; ++tb) {
    short8 kb0 = *(const short8*)&Ks[(wave * 32 + tb * 16 + lrow) * KS_STRIDE + lgrp * 8];
    short8 kb1 = *(const short8*)&Ks[(wave * 32 + tb * 16 + lrow) * KS_STRIDE + 32 + lgrp * 8];
#pragma unroll
    for (int qb = 0; qb < 4; ++qb) {
      floatx4 st = {};
      st = __builtin_amdgcn_mfma_f32_16x16x32_bf16(kb0, qa[qb][0], st, 0, 0, 0);
      st = __builtin_amdgcn_mfma_f32_16x16x32_bf16(kb1, qa[qb][1], st, 0, 0, 0);
      // C layout: lane holds q = qb*16 + lrow (col), t = tw + tb*16 + lgrp*4 + r (row)
      float p0 = exp2f(st[0]), p1 = exp2f(st[1]);
      float p2 = exp2f(st[2]), p3 = exp2f(st[3]);
      if (MASKED) {
        const int qcol = q0 + qb * 16 + lrow;
        const int tbase = tw + tb * 16 + lgrp * 4;
        p0 = (tbase     <= qcol) ? p0 : 0.0f;
        p1 = (tbase + 1 <= qcol) ? p1 : 0.0f;
        p2 = (tbase + 2 <= qcol) ? p2 : 0.0f;
        p3 = (tbase + 3 <= qcol) ? p3 : 0.0f;
      }
      l[qb] += (p0 + p1) + (p2 + p3);
      uint2 pu;
      pu.x = (fbits(p0) >> 16) | (fbits(p1) & 0xFFFF0000u);  // trunc-pack
      pu.y = (fbits(p2) >> 16) | (fbits(p3) & 0xFFFF0000u);
      *(uint2*)&Psw[(qb * 16 + lrow) * PS_STRIDE + tb * 16 + lgrp * 4] = pu;
    }
  }
  // PV over this wave's 32-t slice: A = P[q][t32], B = V[t32][hd]
  short8 vb[4];
#pragma unroll
  for (int hb = 0; hb < 4; ++hb)
    vb[hb] = *(const short8*)&Vs[(hb * 16 + lrow) * VS_STRIDE + wave * 32 + lgrp * 8];
#pragma unroll
  for (int qb = 0; qb < 4; ++qb) {
    short8 pa = *(const short8*)&Psw[(qb * 16 + lrow) * PS_STRIDE + lgrp * 8];
#pragma unroll
    for (int hb = 0; hb < 4; ++hb)
      o[qb][hb] = __builtin_amdgcn_mfma_f32_16x16x32_bf16(pa, vb[hb], o[qb][hb], 0, 0, 0);
  }
}

// grid (32 bh, 32 qt): linear id % 8 = bh % 8 -> one bh per XCD (L2 locality).
// qt reversed: heavy diagonal blocks first. block 256 = 4 waves (t-split).
// LDS 56320 B -> 2 blocks/CU.
__global__ __launch_bounds__(256) void k_flash(const unsigned short* __restrict__ q_n,
                                               const unsigned short* __restrict__ k_n,
                                               const unsigned short* __restrict__ VT,
                                               unsigned short* __restrict__ ctx) {
  const int S = 2048, D = 1024;
  const int bh = blockIdx.x, b = bh >> 4, h = bh & 15;
  const int qt = 31 - (int)blockIdx.y;
  const int q0 = qt * 64;
  const int tid = threadIdx.x, wave = tid >> 6, lane = tid & 63;
  const int lrow = lane & 15, lgrp = lane >> 4;

  __shared__ __align__(16) unsigned char smem[56320];
  unsigned short* Ks  = (unsigned short*)smem;                    // 128*72*2 = 18432
  unsigned short* Vs  = (unsigned short*)(smem + 18432);          //  64*136*2 = 17408
  unsigned short* Psw = (unsigned short*)(smem + 35840) + wave * 64 * PS_STRIDE; // 4*5120
  float* buf0 = (float*)smem;            // post-loop alias over Ks+Vs (16 KB)
  float* buf1 = (float*)(smem + 16384);  // (16 KB)  — 32 KB <= 35840 OK
  float* Lbuf = (float*)(smem + 35840);  // post-loop alias over Ps (4*64 floats)

  const unsigned short* kg = k_n + (size_t)(b * S) * D + h * 64;
  const unsigned short* vg = VT + (size_t)bh * 64 * S;
  const int ksr = tid >> 3, ksc = (tid & 7) * 8;    // K staging: 32 rows/pass
  const int vsr = tid >> 4, vsc = (tid & 15) * 8;   // V staging: 16 rows/pass

  // qa[qb]: B-frag, lane n = q = q0 + qb*16 + lrow, k = hd = lgrp*8 + j (+32)
  short8 qa[4][2];
#pragma unroll
  for (int qb = 0; qb < 4; ++qb) {
    const unsigned short* qp = q_n + (size_t)(b * S + q0 + qb * 16 + lrow) * D + h * 64;
    qa[qb][0] = *(const short8*)(qp + lgrp * 8);
    qa[qb][1] = *(const short8*)(qp + 32 + lgrp * 8);
  }
  floatx4 o[4][4] = {};
  float l[4] = {};

  const int tend = q0 + 64;
  for (int t0 = 0; t0 < tend; t0 += 128) {
#pragma unroll
    for (int j = 0; j < 4; ++j) {
      int r = ksr + j * 32;
      *(int4*)&Ks[r * KS_STRIDE + ksc] = *(const int4*)(kg + (size_t)(t0 + r) * D + ksc);
    }
#pragma unroll
    for (int j = 0; j < 4; ++j) {
      int r = vsr + j * 16;
      *(int4*)&Vs[r * VS_STRIDE + vsc] = *(const int4*)(vg + (size_t)r * S + t0 + vsc);
    }
    __syncthreads();
    if (t0 + 128 <= q0)
      attn_step<false>(t0, q0, wave, qa, Ks, Vs, Psw, o, l, lrow, lgrp);
    else
      attn_step<true>(t0, q0, wave, qa, Ks, Vs, Psw, o, l, lrow, lgrp);
    __syncthreads();
  }

  // ---- cross-wave reductions (O and l are t-partial per wave) ----
  // l: sum over lgrp within wave, publish per wave, sum at final store.
#pragma unroll
  for (int qb = 0; qb < 4; ++qb) {
    l[qb] += __shfl_xor(l[qb], 16, 64);
    l[qb] += __shfl_xor(l[qb], 32, 64);
  }
  if (lane < 16) {
#pragma unroll
    for (int qb = 0; qb < 4; ++qb)
      Lbuf[wave * 64 + qb * 16 + lrow] = l[qb];
  }
  // O tree: waves 2,3 publish; 0,1 add; 1 publishes; 0 adds; 0 publishes.
  if (wave == 2 || wave == 3) {
    float* bf = (wave == 2) ? buf0 : buf1;
#pragma unroll
    for (int qb = 0; qb < 4; ++qb)
#pragma unroll
      for (int hb = 0; hb < 4; ++hb)
#pragma unroll
        for (int r = 0; r < 4; ++r)
          bf[(qb * 16 + lgrp * 4 + r) * 64 + hb * 16 + lrow] = o[qb][hb][r];
  }
  __syncthreads();
  if (wave == 0 || wave == 1) {
    float* bf = (wave == 0) ? buf0 : buf1;
#pragma unroll
    for (int qb = 0; qb < 4; ++qb)
#pragma unroll
      for (int hb = 0; hb < 4; ++hb)
#pragma unroll
        for (int r = 0; r < 4; ++r)
          o[qb][hb][r] += bf[(qb * 16 + lgrp * 4 + r) * 64 + hb * 16 + lrow];
    if (wave == 1)
#pragma unroll
      for (int qb = 0; qb < 4; ++qb)
#pragma unroll
        for (int hb = 0; hb < 4; ++hb)
#pragma unroll
          for (int r = 0; r < 4; ++r)
            buf1[(qb * 16 + lgrp * 4 + r) * 64 + hb * 16 + lrow] = o[qb][hb][r];
  }
  __syncthreads();
  if (wave == 0) {
#pragma unroll
    for (int qb = 0; qb < 4; ++qb)
#pragma unroll
      for (int hb = 0; hb < 4; ++hb)
#pragma unroll
        for (int r = 0; r < 4; ++r) {
          float v = o[qb][hb][r] + buf1[(qb * 16 + lgrp * 4 + r) * 64 + hb * 16 + lrow];
          buf0[(qb * 16 + lgrp * 4 + r) * 64 + hb * 16 + lrow] = v;
        }
  }
  __syncthreads();
  // ---- distributed normalize + store: thread -> (q = tid>>2, 16 hd cols) ----
  {
    const int q = tid >> 2, cb = tid & 3;
    float lq = Lbuf[q] + Lbuf[64 + q] + Lbuf[128 + q] + Lbuf[192 + q];
    float inv = 1.0f / lq;
    const float* src = buf0 + q * 64 + cb * 16;
    short8 w0, w1;
#pragma unroll
    for (int i = 0; i < 8; ++i) ((unsigned short*)&w0)[i] = f2bf(src[i] * inv);
#pragma unroll
    for (int i = 0; i < 8; ++i) ((unsigned short*)&w1)[i] = f2bf(src[8 + i] * inv);
    unsigned short* op = ctx + (size_t)(b * S + q0 + q) * D + h * 64 + cb * 16;
    *(short8*)op = w0;
    *(short8*)(op + 8) = w1;
  }
}

// ---------------------------------- launch ----------------------------------
extern "C" void kernel_launch(void* const* d_in, const int* in_sizes, int n_in,
                              void* d_out, int out_size, void* d_ws, size_t ws_size,
                              hipStream_t stream) {
  const float* x       = (const float*)d_in[0];   // [2,2048,1024] fp32
  const float* W_qkv   = (const float*)d_in[1];   // [1024,3072] fp32
  const float* q_scale = (const float*)d_in[2];   // [1024] fp32
  const float* k_scale = (const float*)d_in[3];   // [1024] fp32
  const float* W_out   = (const float*)d_in[4];   // [1024,1024] fp32
  float* out = (float*)d_out;                     // [2,2048,1024] fp32
  char* ws = (char*)d_ws;
  unsigned short* WT_qkv = (unsigned short*)(ws + 0);         //  6291456
  unsigned short* WT_out = (unsigned short*)(ws + 6291456);   //  2097152
  unsigned short* qkv    = (unsigned short*)(ws + 8388608);   // 25165824
  unsigned short* q_nb   = (unsigned short*)(ws + 33554432);  //  8388608
  unsigned short* k_nb   = (unsigned short*)(ws + 41943040);  //  8388608
  unsigned short* VT     = (unsigned short*)(ws + 50331648);  //  8388608
  unsigned short* x_bf   = (unsigned short*)(ws + 58720256);  //  8388608 -> 64 MiB
  unsigned short* ctx    = qkv;  // alias: qkv dead after k_lnv

  k_prep<<<8192, 256, 0, stream>>>(x, W_qkv, W_out, x_bf, WT_qkv, WT_out);
  k_gemm_bt<128, false><<<dim3(32, 24), 256, 0, stream>>>(x_bf, WT_qkv, qkv, 4096, 3072, 1024);
  k_lnv<<<8192, 256, 0, stream>>>(qkv, q_scale, k_scale, q_nb, k_nb, VT);
  k_flash<<<dim3(32, 32), 256, 0, stream>>>(q_nb, k_nb, VT, ctx);
  k_gemm_bt<64, true><<<dim3(64, 8), 256, 0, stream>>>(ctx, WT_out, out, 4096, 1024, 1024);
}

// Round 9
// 192.164 us; speedup vs baseline: 1.0603x; 1.0603x over previous
//
#include <hip/hip_runtime.h>
#include <cstdint>
#include <cstddef>

typedef __attribute__((ext_vector_type(8))) short short8;   // 8 bf16 = 4 VGPRs (MFMA A/B frag)
typedef __attribute__((ext_vector_type(4))) float floatx4;  // MFMA C/D frag

__device__ __forceinline__ float bf2f(unsigned short u) {
  union { unsigned int i; float f; } c; c.i = ((unsigned int)u) << 16; return c.f;
}
__device__ __forceinline__ unsigned short f2bf(float f) {
  union { float f; unsigned int i; } c; c.f = f;
  unsigned int r = c.i + 0x7fffu + ((c.i >> 16) & 1u);  // round-nearest-even
  return (unsigned short)(r >> 16);
}
__device__ __forceinline__ unsigned int fbits(float f) {
  union { float f; unsigned int i; } c; c.f = f; return c.i;
}

// async global->LDS, 16 B per lane; LDS dest = wave-uniform base + lane*16 (m97/m104)
__device__ __forceinline__ void glds16(const unsigned short* g, unsigned short* l) {
  __builtin_amdgcn_global_load_lds((const __attribute__((address_space(1))) void*)g,
                                   (__attribute__((address_space(3))) void*)l, 16, 0, 0);
}

// ---- 32x32 transpose+cvt tile helper (256 threads, 4 rows/thread) ----
__device__ __forceinline__ void tr_tile(const float* __restrict__ in,
                                        unsigned short* __restrict__ out,
                                        int R, int C, int bx, int by, int tid,
                                        unsigned short (*t)[33]) {
  const int cx = tid & 31, rl = tid >> 5;
#pragma unroll
  for (int i = 0; i < 4; ++i)
    t[rl + i * 8][cx] = f2bf(in[(size_t)(by * 32 + rl + i * 8) * C + bx * 32 + cx]);
  __syncthreads();
  const int oc = by * 32 + cx;
#pragma unroll
  for (int i = 0; i < 4; ++i)
    out[(size_t)(bx * 32 + rl + i * 8) * R + oc] = t[cx][rl + i * 8];
}

// ---- fused prep: W_qkv^T (3072 blks) + W_out^T (1024 blks) + x cvt (4096 blks) ----
__global__ __launch_bounds__(256) void k_prep(const float* __restrict__ x,
                                              const float* __restrict__ Wq,
                                              const float* __restrict__ Wo,
                                              unsigned short* __restrict__ x_bf,
                                              unsigned short* __restrict__ WTq,
                                              unsigned short* __restrict__ WTo) {
  __shared__ unsigned short t[32][33];
  const int bid = blockIdx.x, tid = threadIdx.x;
  if (bid < 3072) {
    tr_tile(Wq, WTq, 1024, 3072, bid % 96, bid / 96, tid, t);
  } else if (bid < 4096) {
    int v = bid - 3072;
    tr_tile(Wo, WTo, 1024, 1024, v & 31, v >> 5, tid, t);
  } else {
    int i = (bid - 4096) * 256 + tid;
    float4 v = ((const float4*)x)[i];
    ushort4 o = { f2bf(v.x), f2bf(v.y), f2bf(v.z), f2bf(v.w) };
    ((ushort4*)x_bf)[i] = o;
  }
}

// ---------------- GEMM: C[M][N] = A[M][K] * BT[N][K]^T, bf16 in ----------------
// m97 structure + r9: BK=64 via TWO glds16 buffers (each [rows][32] contiguous,
// glds lane-contract intact) -> one barrier pair per 64-K instead of 32-K,
// halving the vmcnt(0)+s_barrier drain stalls. LDS 32 KB (not m132's 64 KB).
template <int MT, bool F32OUT>
__global__ __launch_bounds__(256) void k_gemm_bt(const unsigned short* __restrict__ A,
                                                 const unsigned short* __restrict__ BT,
                                                 void* __restrict__ Cout,
                                                 int M, int N, int K) {
  constexpr int NI = MT / 32;  // per-wave m-frag count (4 or 2)
  __shared__ unsigned short As[2][MT * 32];
  __shared__ unsigned short Bs[2][128 * 32];
  const int bm = blockIdx.x * MT, bn = blockIdx.y * 128;
  const int tid = threadIdx.x;
  const int wave = tid >> 6, lane = tid & 63;
  const int wm = (wave & 1) * (MT / 2), wn = (wave >> 1) * 64;
  const int lrow = lane & 15, lgrp = lane >> 4;
  floatx4 acc[NI][4] = {};

  const int lr4 = lane >> 2, lc8 = (lane & 3) * 8;
  const int br0 = wave * 32;
  const unsigned short* Bg0 = BT + (size_t)(bn + br0 + lr4) * K + lc8;
  const unsigned short* Bg1 = BT + (size_t)(bn + br0 + 16 + lr4) * K + lc8;
  const int ar0 = wave * (MT / 4);
  const unsigned short* Ag0 = A + (size_t)(bm + ar0 + lr4) * K + lc8;
  const unsigned short* Ag1 = A + (size_t)(bm + ar0 + 16 + lr4) * K + lc8;  // MT==128 only

  for (int k0 = 0; k0 < K; k0 += 64) {
#pragma unroll
    for (int u = 0; u < 2; ++u) {
      const int ko = k0 + u * 32;
      glds16(Ag0 + ko, &As[u][ar0 * 32]);
      if (MT == 128) glds16(Ag1 + ko, &As[u][(ar0 + 16) * 32]);
      glds16(Bg0 + ko, &Bs[u][br0 * 32]);
      glds16(Bg1 + ko, &Bs[u][(br0 + 16) * 32]);
    }
    __syncthreads();   // drains vmcnt (glds) before any wave reads LDS
#pragma unroll
    for (int u = 0; u < 2; ++u) {
      short8 a[NI], bfr[4];
#pragma unroll
      for (int i = 0; i < NI; ++i)
        a[i] = *(const short8*)&As[u][(wm + i * 16 + lrow) * 32 + lgrp * 8];
#pragma unroll
      for (int j = 0; j < 4; ++j)
        bfr[j] = *(const short8*)&Bs[u][(wn + j * 16 + lrow) * 32 + lgrp * 8];
#pragma unroll
      for (int i = 0; i < NI; ++i)
#pragma unroll
        for (int j = 0; j < 4; ++j)
          acc[i][j] = __builtin_amdgcn_mfma_f32_16x16x32_bf16(a[i], bfr[j], acc[i][j], 0, 0, 0);
    }
    __syncthreads();
  }
#pragma unroll
  for (int i = 0; i < NI; ++i)
#pragma unroll
    for (int j = 0; j < 4; ++j)
#pragma unroll
      for (int r = 0; r < 4; ++r) {
        int m = bm + wm + i * 16 + lgrp * 4 + r;
        int n = bn + wn + j * 16 + lrow;
        if (F32OUT)
          ((float*)Cout)[(size_t)m * N + n] = acc[i][j][r];
        else
          ((unsigned short*)Cout)[(size_t)m * N + n] = f2bf(acc[i][j][r]);
      }
}

// ---- fused LN (4096 blks) + V transpose (4096 blks); both read qkv ----
// LN: q out folded by 0.125*log2(e) so flash uses exp2 directly.
__global__ __launch_bounds__(256) void k_lnv(const unsigned short* __restrict__ qkv,
                                             const float* __restrict__ q_scale,
                                             const float* __restrict__ k_scale,
                                             unsigned short* __restrict__ q_n,
                                             unsigned short* __restrict__ k_n,
                                             unsigned short* __restrict__ VT) {
  const int bid = blockIdx.x, tid = threadIdx.x;
  if (bid < 4096) {
    const int tok = bid;
    const int wave = tid >> 6, lane = tid & 63;
    __shared__ float red[2][4];
    const unsigned short* row = qkv + (size_t)tok * 3072;
#pragma unroll
    for (int seg = 0; seg < 2; ++seg) {
      const unsigned short* p  = row + seg * 1024;
      const float* sc = seg ? k_scale : q_scale;
      unsigned short* outp = (seg ? k_n : q_n) + (size_t)tok * 1024;
      ushort4 u = *(const ushort4*)&p[tid * 4];
      float xv[4] = { bf2f(u.x), bf2f(u.y), bf2f(u.z), bf2f(u.w) };
      float sum = xv[0] + xv[1] + xv[2] + xv[3];
      float sq  = xv[0]*xv[0] + xv[1]*xv[1] + xv[2]*xv[2] + xv[3]*xv[3];
      for (int off = 32; off; off >>= 1) {
        sum += __shfl_down(sum, off, 64);
        sq  += __shfl_down(sq,  off, 64);
      }
      if (lane == 0) { red[0][wave] = sum; red[1][wave] = sq; }
      __syncthreads();
      sum = red[0][0] + red[0][1] + red[0][2] + red[0][3];
      sq  = red[1][0] + red[1][1] + red[1][2] + red[1][3];
      __syncthreads();
      float mean = sum * (1.0f / 1024.0f);
      float var  = sq * (1.0f / 1024.0f) - mean * mean;
      float rstd = rsqrtf(var + 1e-6f);
      if (seg == 0) rstd *= 0.18033688011112042f;  // 0.125 * log2(e)
      float4 su = *(const float4*)&sc[tid * 4];
      ushort4 o;
      o.x = f2bf((xv[0] - mean) * rstd * su.x);
      o.y = f2bf((xv[1] - mean) * rstd * su.y);
      o.z = f2bf((xv[2] - mean) * rstd * su.z);
      o.w = f2bf((xv[3] - mean) * rstd * su.w);
      *(ushort4*)&outp[tid * 4] = o;
    }
  } else {
    // V transpose tile: v-part [b,s,h*64+hd] -> VT[(b*16+h)*64+hd][s]
    __shared__ unsigned short t[32][33];
    const int v = bid - 4096;
    const int bh = v & 31, b = bh >> 4, h = bh & 15;
    const int sy = (v >> 5) & 63, hx = v >> 11;   // s-tile 0..63, hd-tile 0..1
    const int cx = tid & 31, rl = tid >> 5;
#pragma unroll
    for (int i = 0; i < 4; ++i)
      t[rl + i * 8][cx] =
        qkv[(size_t)(b * 2048 + sy * 32 + rl + i * 8) * 3072 + 2048 + h * 64 + hx * 32 + cx];
    __syncthreads();
#pragma unroll
    for (int i = 0; i < 4; ++i)
      VT[((size_t)bh * 64 + hx * 32 + rl + i * 8) * 2048 + sy * 32 + cx] = t[cx][rl + i * 8];
  }
}

// ------------------------------ flash attention ------------------------------
// r9 HYBRID 2q x 2t wave split: wave (wq,wt) owns 32 q x 64 t. K/V LDS reads
// 2x-redundant (r7: 4x, r8: 1x) = 20 b128/step/wave; tail = ONE pairwise add
// across the wt pair (r8's 3-level tree killed the win). o[2][4]=32 VGPRs.
// Fixed-max softmax (m=0, r4/r5); trunc-packed P; l exact fp32.
// All LDS strides multiples of 8 shorts (16 B) — b128 alignment (r6 lesson).

#define KS_STRIDE 72   // 144 B = 9*16
#define VS_STRIDE 136  // 272 B = 17*16
#define PS_STRIDE 72   // per-wave Ps [32 q][64 t] pad->72

template <bool MASKED>
__device__ __forceinline__ void attn_step(int t0, int q0, int wq, int wt,
    const short8 (&qa)[2][2],
    const unsigned short* Ks, const unsigned short* Vs, unsigned short* Psw,
    floatx4 (&o)[2][4], float (&l)[2], int lrow, int lgrp) {
  const int twbase = wt * 64;
#pragma unroll
  for (int tb = 0; tb < 4; ++tb) {
    short8 kb0 = *(const short8*)&Ks[(twbase + tb * 16 + lrow) * KS_STRIDE + lgrp * 8];
    short8 kb1 = *(const short8*)&Ks[(twbase + tb * 16 + lrow) * KS_STRIDE + 32 + lgrp * 8];
#pragma unroll
    for (int qb = 0; qb < 2; ++qb) {
      floatx4 st = {};
      st = __builtin_amdgcn_mfma_f32_16x16x32_bf16(kb0, qa[qb][0], st, 0, 0, 0);
      st = __builtin_amdgcn_mfma_f32_16x16x32_bf16(kb1, qa[qb][1], st, 0, 0, 0);
      // C layout: lane holds t = twbase+tb*16+lgrp*4+r (row), q = qb*16+lrow (col)
      float p0 = exp2f(st[0]), p1 = exp2f(st[1]);
      float p2 = exp2f(st[2]), p3 = exp2f(st[3]);
      if (MASKED) {
        const int qcol = q0 + wq * 32 + qb * 16 + lrow;
        const int tbase = t0 + twbase + tb * 16 + lgrp * 4;
        p0 = (tbase     <= qcol) ? p0 : 0.0f;
        p1 = (tbase + 1 <= qcol) ? p1 : 0.0f;
        p2 = (tbase + 2 <= qcol) ? p2 : 0.0f;
        p3 = (tbase + 3 <= qcol) ? p3 : 0.0f;
      }
      l[qb] += (p0 + p1) + (p2 + p3);
      uint2 pu;
      pu.x = (fbits(p0) >> 16) | (fbits(p1) & 0xFFFF0000u);  // trunc-pack
      pu.y = (fbits(p2) >> 16) | (fbits(p3) & 0xFFFF0000u);
      *(uint2*)&Psw[(qb * 16 + lrow) * PS_STRIDE + tb * 16 + lgrp * 4] = pu;
    }
  }
  // PV over this wave's 64-t slice: A = P[q][t], B = V[t][hd] (from Vs[hd][t])
#pragma unroll
  for (int kk = 0; kk < 2; ++kk) {
    short8 pa0 = *(const short8*)&Psw[lrow * PS_STRIDE + kk * 32 + lgrp * 8];
    short8 pa1 = *(const short8*)&Psw[(16 + lrow) * PS_STRIDE + kk * 32 + lgrp * 8];
#pragma unroll
    for (int hb = 0; hb < 4; ++hb) {
      short8 vb = *(const short8*)&Vs[(hb * 16 + lrow) * VS_STRIDE + twbase + kk * 32 + lgrp * 8];
      o[0][hb] = __builtin_amdgcn_mfma_f32_16x16x32_bf16(pa0, vb, o[0][hb], 0, 0, 0);
      o[1][hb] = __builtin_amdgcn_mfma_f32_16x16x32_bf16(pa1, vb, o[1][hb], 0, 0, 0);
    }
  }
}

// grid (32 bh, 32 qt): linear id % 8 = bh % 8 -> one bh per XCD (L2 locality).
// qt reversed: heavy diagonal blocks first. block 256 = 4 waves (2q x 2t).
// LDS 54272 B; 3 blocks/CU (3*54272 = 162816 <= 163840).
__global__ __launch_bounds__(256) void k_flash(const unsigned short* __restrict__ q_n,
                                               const unsigned short* __restrict__ k_n,
                                               const unsigned short* __restrict__ VT,
                                               unsigned short* __restrict__ ctx) {
  const int S = 2048, D = 1024;
  const int bh = blockIdx.x, b = bh >> 4, h = bh & 15;
  const int qt = 31 - (int)blockIdx.y;
  const int q0 = qt * 64;
  const int tid = threadIdx.x, wave = tid >> 6, lane = tid & 63;
  const int wq = wave >> 1, wt = wave & 1;
  const int lrow = lane & 15, lgrp = lane >> 4;

  __shared__ __align__(16) unsigned char smem[54272];
  unsigned short* Ks  = (unsigned short*)smem;                    // 128*72*2 = 18432
  unsigned short* Vs  = (unsigned short*)(smem + 18432);          //  64*136*2 = 17408
  unsigned short* Psw = (unsigned short*)(smem + 35840) + wave * 32 * PS_STRIDE; // 4*4608
  // tail aliases (over Ks region, dead after loop): 2 x 32q x 64hd fp32, stride 68
  float* buf  = (float*)smem;                                     // 2*32*68*4 = 17408
  float* Lbuf = (float*)(smem + 17408);                           // 64 floats = 256 B

  const unsigned short* kg = k_n + (size_t)(b * S) * D + h * 64;
  const unsigned short* vg = VT + (size_t)bh * 64 * S;
  const int ksr = tid >> 3, ksc = (tid & 7) * 8;    // K staging: 32 rows/pass
  const int vsr = tid >> 4, vsc = (tid & 15) * 8;   // V staging: 16 rows/pass

  // qa[qb]: B-frag, lane n = q = q0 + wq*32 + qb*16 + lrow, k = hd = lgrp*8+j (+32)
  short8 qa[2][2];
#pragma unroll
  for (int qb = 0; qb < 2; ++qb) {
    const unsigned short* qp =
        q_n + (size_t)(b * S + q0 + wq * 32 + qb * 16 + lrow) * D + h * 64;
    qa[qb][0] = *(const short8*)(qp + lgrp * 8);
    qa[qb][1] = *(const short8*)(qp + 32 + lgrp * 8);
  }
  floatx4 o[2][4] = {};
  float l[2] = {};

  const int tend = q0 + 64;
  for (int t0 = 0; t0 < tend; t0 += 128) {
#pragma unroll
    for (int j = 0; j < 4; ++j) {
      int r = ksr + j * 32;
      *(int4*)&Ks[r * KS_STRIDE + ksc] = *(const int4*)(kg + (size_t)(t0 + r) * D + ksc);
    }
#pragma unroll
    for (int j = 0; j < 4; ++j) {
      int r = vsr + j * 16;
      *(int4*)&Vs[r * VS_STRIDE + vsc] = *(const int4*)(vg + (size_t)r * S + t0 + vsc);
    }
    __syncthreads();
    const bool half = (tend - t0) < 128;   // last 64-t step: wt=1's slice is void
    if (!(half && wt == 1)) {
      if (t0 + 128 <= q0)
        attn_step<false>(t0, q0, wq, wt, qa, Ks, Vs, Psw, o, l, lrow, lgrp);
      else
        attn_step<true>(t0, q0, wq, wt, qa, Ks, Vs, Psw, o, l, lrow, lgrp);
    }
    __syncthreads();
  }

  // ---- tail: combine the wt pair (O and l are t-partial per wave) ----
#pragma unroll
  for (int qb = 0; qb < 2; ++qb) {
    l[qb] += __shfl_xor(l[qb], 16, 64);
    l[qb] += __shfl_xor(l[qb], 32, 64);
  }
  if (wt == 1) {
    if (lane < 16) {
      Lbuf[wq * 32 + lrow]      = l[0];
      Lbuf[wq * 32 + 16 + lrow] = l[1];
    }
    float* bf = buf + wq * 32 * 68;
#pragma unroll
    for (int qb = 0; qb < 2; ++qb)
#pragma unroll
      for (int hb = 0; hb < 4; ++hb)
#pragma unroll
        for (int r = 0; r < 4; ++r)
          bf[(qb * 16 + lgrp * 4 + r) * 68 + hb * 16 + lrow] = o[qb][hb][r];
  }
  __syncthreads();
  if (wt == 0) {
    float* bf = buf + wq * 32 * 68;
#pragma unroll
    for (int qb = 0; qb < 2; ++qb) {
      l[qb] += Lbuf[wq * 32 + qb * 16 + lrow];
#pragma unroll
      for (int hb = 0; hb < 4; ++hb)
#pragma unroll
        for (int r = 0; r < 4; ++r)
          o[qb][hb][r] += bf[(qb * 16 + lgrp * 4 + r) * 68 + hb * 16 + lrow];
    }
    // inv per (qb,r): l value lives at lane lrow = lgrp*4+r (replicated over lgrp)
    unsigned short* op = ctx + (size_t)(b * S + q0 + wq * 32) * D + h * 64;
#pragma unroll
    for (int qb = 0; qb < 2; ++qb)
#pragma unroll
      for (int r = 0; r < 4; ++r) {
        float inv = 1.0f / __shfl(l[qb], lgrp * 4 + r, 64);
        int row = qb * 16 + lgrp * 4 + r;
#pragma unroll
        for (int hb = 0; hb < 4; ++hb)
          op[(size_t)row * D + hb * 16 + lrow] = f2bf(o[qb][hb][r] * inv);
      }
  }
}

// ---------------------------------- launch ----------------------------------
extern "C" void kernel_launch(void* const* d_in, const int* in_sizes, int n_in,
                              void* d_out, int out_size, void* d_ws, size_t ws_size,
                              hipStream_t stream) {
  const float* x       = (const float*)d_in[0];   // [2,2048,1024] fp32
  const float* W_qkv   = (const float*)d_in[1];   // [1024,3072] fp32
  const float* q_scale = (const float*)d_in[2];   // [1024] fp32
  const float* k_scale = (const float*)d_in[3];   // [1024] fp32
  const float* W_out   = (const float*)d_in[4];   // [1024,1024] fp32
  float* out = (float*)d_out;                     // [2,2048,1024] fp32
  char* ws = (char*)d_ws;
  unsigned short* WT_qkv = (unsigned short*)(ws + 0);         //  6291456
  unsigned short* WT_out = (unsigned short*)(ws + 6291456);   //  2097152
  unsigned short* qkv    = (unsigned short*)(ws + 8388608);   // 25165824
  unsigned short* q_nb   = (unsigned short*)(ws + 33554432);  //  8388608
  unsigned short* k_nb   = (unsigned short*)(ws + 41943040);  //  8388608
  unsigned short* VT     = (unsigned short*)(ws + 50331648);  //  8388608
  unsigned short* x_bf   = (unsigned short*)(ws + 58720256);  //  8388608 -> 64 MiB
  unsigned short* ctx    = qkv;  // alias: qkv dead after k_lnv

  k_prep<<<8192, 256, 0, stream>>>(x, W_qkv, W_out, x_bf, WT_qkv, WT_out);
  k_gemm_bt<128, false><<<dim3(32, 24), 256, 0, stream>>>(x_bf, WT_qkv, qkv, 4096, 3072, 1024);
  k_lnv<<<8192, 256, 0, stream>>>(qkv, q_scale, k_scale, q_nb, k_nb, VT);
  k_flash<<<dim3(32, 32), 256, 0, stream>>>(q_nb, k_nb, VT, ctx);
  k_gemm_bt<64, true><<<dim3(64, 8), 256, 0, stream>>>(ctx, WT_out, out, 4096, 1024, 1024);
}

// Round 10
// 185.062 us; speedup vs baseline: 1.1010x; 1.0384x over previous
//
#include <hip/hip_runtime.h>
#include <cstdint>
#include <cstddef>

typedef __attribute__((ext_vector_type(8))) short short8;   // 8 bf16 = 4 VGPRs (MFMA A/B frag)
typedef __attribute__((ext_vector_type(4))) float floatx4;  // MFMA C/D frag

__device__ __forceinline__ float bf2f(unsigned short u) {
  union { unsigned int i; float f; } c; c.i = ((unsigned int)u) << 16; return c.f;
}
__device__ __forceinline__ unsigned short f2bf(float f) {
  union { float f; unsigned int i; } c; c.f = f;
  unsigned int r = c.i + 0x7fffu + ((c.i >> 16) & 1u);  // round-nearest-even
  return (unsigned short)(r >> 16);
}
__device__ __forceinline__ unsigned int fbits(float f) {
  union { float f; unsigned int i; } c; c.f = f; return c.i;
}

// async global->LDS, 16 B per lane; LDS dest = wave-uniform base + lane*16 (m97/m104)
__device__ __forceinline__ void glds16(const unsigned short* g, unsigned short* l) {
  __builtin_amdgcn_global_load_lds((const __attribute__((address_space(1))) void*)g,
                                   (__attribute__((address_space(3))) void*)l, 16, 0, 0);
}

// ---- 32x32 transpose+cvt tile helper (256 threads, 4 rows/thread) ----
__device__ __forceinline__ void tr_tile(const float* __restrict__ in,
                                        unsigned short* __restrict__ out,
                                        int R, int C, int bx, int by, int tid,
                                        unsigned short (*t)[33]) {
  const int cx = tid & 31, rl = tid >> 5;
#pragma unroll
  for (int i = 0; i < 4; ++i)
    t[rl + i * 8][cx] = f2bf(in[(size_t)(by * 32 + rl + i * 8) * C + bx * 32 + cx]);
  __syncthreads();
  const int oc = by * 32 + cx;
#pragma unroll
  for (int i = 0; i < 4; ++i)
    out[(size_t)(bx * 32 + rl + i * 8) * R + oc] = t[cx][rl + i * 8];
}

// ---- fused prep: W_qkv^T (3072 blks) + W_out^T (1024 blks) + x cvt (4096 blks) ----
__global__ __launch_bounds__(256) void k_prep(const float* __restrict__ x,
                                              const float* __restrict__ Wq,
                                              const float* __restrict__ Wo,
                                              unsigned short* __restrict__ x_bf,
                                              unsigned short* __restrict__ WTq,
                                              unsigned short* __restrict__ WTo) {
  __shared__ unsigned short t[32][33];
  const int bid = blockIdx.x, tid = threadIdx.x;
  if (bid < 3072) {
    tr_tile(Wq, WTq, 1024, 3072, bid % 96, bid / 96, tid, t);
  } else if (bid < 4096) {
    int v = bid - 3072;
    tr_tile(Wo, WTo, 1024, 1024, v & 31, v >> 5, tid, t);
  } else {
    int i = (bid - 4096) * 256 + tid;
    float4 v = ((const float4*)x)[i];
    ushort4 o = { f2bf(v.x), f2bf(v.y), f2bf(v.z), f2bf(v.w) };
    ((ushort4*)x_bf)[i] = o;
  }
}

// ---------------- GEMM: C[M][N] = A[M][K] * BT[N][K]^T, bf16 in ----------------
// m97 structure + r9: BK=64 via TWO glds16 buffers -> one barrier pair per
// 64-K instead of 32-K (halves barrier-drain stalls). LDS 32 KB.
template <int MT, bool F32OUT>
__global__ __launch_bounds__(256) void k_gemm_bt(const unsigned short* __restrict__ A,
                                                 const unsigned short* __restrict__ BT,
                                                 void* __restrict__ Cout,
                                                 int M, int N, int K) {
  constexpr int NI = MT / 32;  // per-wave m-frag count (4 or 2)
  __shared__ unsigned short As[2][MT * 32];
  __shared__ unsigned short Bs[2][128 * 32];
  const int bm = blockIdx.x * MT, bn = blockIdx.y * 128;
  const int tid = threadIdx.x;
  const int wave = tid >> 6, lane = tid & 63;
  const int wm = (wave & 1) * (MT / 2), wn = (wave >> 1) * 64;
  const int lrow = lane & 15, lgrp = lane >> 4;
  floatx4 acc[NI][4] = {};

  const int lr4 = lane >> 2, lc8 = (lane & 3) * 8;
  const int br0 = wave * 32;
  const unsigned short* Bg0 = BT + (size_t)(bn + br0 + lr4) * K + lc8;
  const unsigned short* Bg1 = BT + (size_t)(bn + br0 + 16 + lr4) * K + lc8;
  const int ar0 = wave * (MT / 4);
  const unsigned short* Ag0 = A + (size_t)(bm + ar0 + lr4) * K + lc8;
  const unsigned short* Ag1 = A + (size_t)(bm + ar0 + 16 + lr4) * K + lc8;  // MT==128 only

  for (int k0 = 0; k0 < K; k0 += 64) {
#pragma unroll
    for (int u = 0; u < 2; ++u) {
      const int ko = k0 + u * 32;
      glds16(Ag0 + ko, &As[u][ar0 * 32]);
      if (MT == 128) glds16(Ag1 + ko, &As[u][(ar0 + 16) * 32]);
      glds16(Bg0 + ko, &Bs[u][br0 * 32]);
      glds16(Bg1 + ko, &Bs[u][(br0 + 16) * 32]);
    }
    __syncthreads();   // drains vmcnt (glds) before any wave reads LDS
#pragma unroll
    for (int u = 0; u < 2; ++u) {
      short8 a[NI], bfr[4];
#pragma unroll
      for (int i = 0; i < NI; ++i)
        a[i] = *(const short8*)&As[u][(wm + i * 16 + lrow) * 32 + lgrp * 8];
#pragma unroll
      for (int j = 0; j < 4; ++j)
        bfr[j] = *(const short8*)&Bs[u][(wn + j * 16 + lrow) * 32 + lgrp * 8];
#pragma unroll
      for (int i = 0; i < NI; ++i)
#pragma unroll
        for (int j = 0; j < 4; ++j)
          acc[i][j] = __builtin_amdgcn_mfma_f32_16x16x32_bf16(a[i], bfr[j], acc[i][j], 0, 0, 0);
    }
    __syncthreads();
  }
#pragma unroll
  for (int i = 0; i < NI; ++i)
#pragma unroll
    for (int j = 0; j < 4; ++j)
#pragma unroll
      for (int r = 0; r < 4; ++r) {
        int m = bm + wm + i * 16 + lgrp * 4 + r;
        int n = bn + wn + j * 16 + lrow;
        if (F32OUT)
          ((float*)Cout)[(size_t)m * N + n] = acc[i][j][r];
        else
          ((unsigned short*)Cout)[(size_t)m * N + n] = f2bf(acc[i][j][r]);
      }
}

// ---- fused LN (4096 blks) + V transpose (4096 blks); both read qkv ----
// LN: q out folded by 0.125*log2(e) so flash uses exp2 directly.
__global__ __launch_bounds__(256) void k_lnv(const unsigned short* __restrict__ qkv,
                                             const float* __restrict__ q_scale,
                                             const float* __restrict__ k_scale,
                                             unsigned short* __restrict__ q_n,
                                             unsigned short* __restrict__ k_n,
                                             unsigned short* __restrict__ VT) {
  const int bid = blockIdx.x, tid = threadIdx.x;
  if (bid < 4096) {
    const int tok = bid;
    const int wave = tid >> 6, lane = tid & 63;
    __shared__ float red[2][4];
    const unsigned short* row = qkv + (size_t)tok * 3072;
#pragma unroll
    for (int seg = 0; seg < 2; ++seg) {
      const unsigned short* p  = row + seg * 1024;
      const float* sc = seg ? k_scale : q_scale;
      unsigned short* outp = (seg ? k_n : q_n) + (size_t)tok * 1024;
      ushort4 u = *(const ushort4*)&p[tid * 4];
      float xv[4] = { bf2f(u.x), bf2f(u.y), bf2f(u.z), bf2f(u.w) };
      float sum = xv[0] + xv[1] + xv[2] + xv[3];
      float sq  = xv[0]*xv[0] + xv[1]*xv[1] + xv[2]*xv[2] + xv[3]*xv[3];
      for (int off = 32; off; off >>= 1) {
        sum += __shfl_down(sum, off, 64);
        sq  += __shfl_down(sq,  off, 64);
      }
      if (lane == 0) { red[0][wave] = sum; red[1][wave] = sq; }
      __syncthreads();
      sum = red[0][0] + red[0][1] + red[0][2] + red[0][3];
      sq  = red[1][0] + red[1][1] + red[1][2] + red[1][3];
      __syncthreads();
      float mean = sum * (1.0f / 1024.0f);
      float var  = sq * (1.0f / 1024.0f) - mean * mean;
      float rstd = rsqrtf(var + 1e-6f);
      if (seg == 0) rstd *= 0.18033688011112042f;  // 0.125 * log2(e)
      float4 su = *(const float4*)&sc[tid * 4];
      ushort4 o;
      o.x = f2bf((xv[0] - mean) * rstd * su.x);
      o.y = f2bf((xv[1] - mean) * rstd * su.y);
      o.z = f2bf((xv[2] - mean) * rstd * su.z);
      o.w = f2bf((xv[3] - mean) * rstd * su.w);
      *(ushort4*)&outp[tid * 4] = o;
    }
  } else {
    // V transpose tile: v-part [b,s,h*64+hd] -> VT[(b*16+h)*64+hd][s]
    __shared__ unsigned short t[32][33];
    const int v = bid - 4096;
    const int bh = v & 31, b = bh >> 4, h = bh & 15;
    const int sy = (v >> 5) & 63, hx = v >> 11;   // s-tile 0..63, hd-tile 0..1
    const int cx = tid & 31, rl = tid >> 5;
#pragma unroll
    for (int i = 0; i < 4; ++i)
      t[rl + i * 8][cx] =
        qkv[(size_t)(b * 2048 + sy * 32 + rl + i * 8) * 3072 + 2048 + h * 64 + hx * 32 + cx];
    __syncthreads();
#pragma unroll
    for (int i = 0; i < 4; ++i)
      VT[((size_t)bh * 64 + hx * 32 + rl + i * 8) * 2048 + sy * 32 + cx] = t[cx][rl + i * 8];
  }
}

// ------------------------------ flash attention ------------------------------
// r10 = r9 hybrid 2q x 2t split, but Ps SHARED per wq pair: the two wt-waves
// write disjoint t-halves of Ps[wq][32 q][136 t] and read back only their own
// half -> no extra sync, and LDS drops 54272 -> 53248 B = 26 x 2KiB granules
// -> 3 blocks/CU (r9's 54272 rounded to 27 granules -> 2 blocks, the regression).
// Fixed-max softmax (m=0); trunc-packed P; l exact fp32.
// All b128 LDS strides multiples of 8 shorts (16 B) — r6 lesson.

#define KS_STRIDE 72   // 144 B = 9*16
#define VS_STRIDE 136  // 272 B = 17*16
#define PS_STRIDE 136  // shared [32 q][128 t] pad->136

template <bool MASKED>
__device__ __forceinline__ void attn_step(int t0, int q0, int wq, int wt,
    const short8 (&qa)[2][2],
    const unsigned short* Ks, const unsigned short* Vs, unsigned short* Psq,
    floatx4 (&o)[2][4], float (&l)[2], int lrow, int lgrp) {
  const int twbase = wt * 64;
#pragma unroll
  for (int tb = 0; tb < 4; ++tb) {
    short8 kb0 = *(const short8*)&Ks[(twbase + tb * 16 + lrow) * KS_STRIDE + lgrp * 8];
    short8 kb1 = *(const short8*)&Ks[(twbase + tb * 16 + lrow) * KS_STRIDE + 32 + lgrp * 8];
#pragma unroll
    for (int qb = 0; qb < 2; ++qb) {
      floatx4 st = {};
      st = __builtin_amdgcn_mfma_f32_16x16x32_bf16(kb0, qa[qb][0], st, 0, 0, 0);
      st = __builtin_amdgcn_mfma_f32_16x16x32_bf16(kb1, qa[qb][1], st, 0, 0, 0);
      // C layout: lane holds t = twbase+tb*16+lgrp*4+r (row), q = qb*16+lrow (col)
      float p0 = exp2f(st[0]), p1 = exp2f(st[1]);
      float p2 = exp2f(st[2]), p3 = exp2f(st[3]);
      if (MASKED) {
        const int qcol = q0 + wq * 32 + qb * 16 + lrow;
        const int tbase = t0 + twbase + tb * 16 + lgrp * 4;
        p0 = (tbase     <= qcol) ? p0 : 0.0f;
        p1 = (tbase + 1 <= qcol) ? p1 : 0.0f;
        p2 = (tbase + 2 <= qcol) ? p2 : 0.0f;
        p3 = (tbase + 3 <= qcol) ? p3 : 0.0f;
      }
      l[qb] += (p0 + p1) + (p2 + p3);
      uint2 pu;
      pu.x = (fbits(p0) >> 16) | (fbits(p1) & 0xFFFF0000u);  // trunc-pack
      pu.y = (fbits(p2) >> 16) | (fbits(p3) & 0xFFFF0000u);
      *(uint2*)&Psq[(qb * 16 + lrow) * PS_STRIDE + twbase + tb * 16 + lgrp * 4] = pu;
    }
  }
  // PV over this wave's 64-t slice: A = P[q][t] (own half), B = V[t][hd]
#pragma unroll
  for (int kk = 0; kk < 2; ++kk) {
    short8 pa0 = *(const short8*)&Psq[lrow * PS_STRIDE + twbase + kk * 32 + lgrp * 8];
    short8 pa1 = *(const short8*)&Psq[(16 + lrow) * PS_STRIDE + twbase + kk * 32 + lgrp * 8];
#pragma unroll
    for (int hb = 0; hb < 4; ++hb) {
      short8 vb = *(const short8*)&Vs[(hb * 16 + lrow) * VS_STRIDE + twbase + kk * 32 + lgrp * 8];
      o[0][hb] = __builtin_amdgcn_mfma_f32_16x16x32_bf16(pa0, vb, o[0][hb], 0, 0, 0);
      o[1][hb] = __builtin_amdgcn_mfma_f32_16x16x32_bf16(pa1, vb, o[1][hb], 0, 0, 0);
    }
  }
}

// grid (32 bh, 32 qt): linear id % 8 = bh % 8 -> one bh per XCD (L2 locality).
// qt reversed: heavy diagonal blocks first. block 256 = 4 waves (2q x 2t).
// LDS 53248 B = 26 x 2KiB -> 3 blocks/CU (159744 <= 163840).
__global__ __launch_bounds__(256) void k_flash(const unsigned short* __restrict__ q_n,
                                               const unsigned short* __restrict__ k_n,
                                               const unsigned short* __restrict__ VT,
                                               unsigned short* __restrict__ ctx) {
  const int S = 2048, D = 1024;
  const int bh = blockIdx.x, b = bh >> 4, h = bh & 15;
  const int qt = 31 - (int)blockIdx.y;
  const int q0 = qt * 64;
  const int tid = threadIdx.x, wave = tid >> 6, lane = tid & 63;
  const int wq = wave >> 1, wt = wave & 1;
  const int lrow = lane & 15, lgrp = lane >> 4;

  __shared__ __align__(16) unsigned char smem[53248];
  unsigned short* Ks  = (unsigned short*)smem;                    // 128*72*2 = 18432
  unsigned short* Vs  = (unsigned short*)(smem + 18432);          //  64*136*2 = 17408
  unsigned short* Psq = (unsigned short*)(smem + 35840) + wq * 32 * PS_STRIDE; // 2*8704
  // tail aliases (dead regions after loop): buf over Ks, Lbuf over Vs start
  float* buf  = (float*)smem;                                     // 2*32*68*4 = 17408
  float* Lbuf = (float*)(smem + 17408);                           // 64 floats

  const unsigned short* kg = k_n + (size_t)(b * S) * D + h * 64;
  const unsigned short* vg = VT + (size_t)bh * 64 * S;
  const int ksr = tid >> 3, ksc = (tid & 7) * 8;    // K staging: 32 rows/pass
  const int vsr = tid >> 4, vsc = (tid & 15) * 8;   // V staging: 16 rows/pass

  // qa[qb]: B-frag, lane n = q = q0 + wq*32 + qb*16 + lrow, k = hd = lgrp*8+j (+32)
  short8 qa[2][2];
#pragma unroll
  for (int qb = 0; qb < 2; ++qb) {
    const unsigned short* qp =
        q_n + (size_t)(b * S + q0 + wq * 32 + qb * 16 + lrow) * D + h * 64;
    qa[qb][0] = *(const short8*)(qp + lgrp * 8);
    qa[qb][1] = *(const short8*)(qp + 32 + lgrp * 8);
  }
  floatx4 o[2][4] = {};
  float l[2] = {};

  const int tend = q0 + 64;
  for (int t0 = 0; t0 < tend; t0 += 128) {
#pragma unroll
    for (int j = 0; j < 4; ++j) {
      int r = ksr + j * 32;
      *(int4*)&Ks[r * KS_STRIDE + ksc] = *(const int4*)(kg + (size_t)(t0 + r) * D + ksc);
    }
#pragma unroll
    for (int j = 0; j < 4; ++j) {
      int r = vsr + j * 16;
      *(int4*)&Vs[r * VS_STRIDE + vsc] = *(const int4*)(vg + (size_t)r * S + t0 + vsc);
    }
    __syncthreads();
    const bool half = (tend - t0) < 128;   // last 64-t step: wt=1's slice is void
    if (!(half && wt == 1)) {
      if (t0 + 128 <= q0)
        attn_step<false>(t0, q0, wq, wt, qa, Ks, Vs, Psq, o, l, lrow, lgrp);
      else
        attn_step<true>(t0, q0, wq, wt, qa, Ks, Vs, Psq, o, l, lrow, lgrp);
    }
    __syncthreads();
  }

  // ---- tail: combine the wt pair (O and l are t-partial per wave) ----
#pragma unroll
  for (int qb = 0; qb < 2; ++qb) {
    l[qb] += __shfl_xor(l[qb], 16, 64);
    l[qb] += __shfl_xor(l[qb], 32, 64);
  }
  if (wt == 1) {
    if (lane < 16) {
      Lbuf[wq * 32 + lrow]      = l[0];
      Lbuf[wq * 32 + 16 + lrow] = l[1];
    }
    float* bf = buf + wq * 32 * 68;
#pragma unroll
    for (int qb = 0; qb < 2; ++qb)
#pragma unroll
      for (int hb = 0; hb < 4; ++hb)
#pragma unroll
        for (int r = 0; r < 4; ++r)
          bf[(qb * 16 + lgrp * 4 + r) * 68 + hb * 16 + lrow] = o[qb][hb][r];
  }
  __syncthreads();
  if (wt == 0) {
    float* bf = buf + wq * 32 * 68;
#pragma unroll
    for (int qb = 0; qb < 2; ++qb) {
      l[qb] += Lbuf[wq * 32 + qb * 16 + lrow];
#pragma unroll
      for (int hb = 0; hb < 4; ++hb)
#pragma unroll
        for (int r = 0; r < 4; ++r)
          o[qb][hb][r] += bf[(qb * 16 + lgrp * 4 + r) * 68 + hb * 16 + lrow];
    }
    // inv per (qb,r): l value lives at lane lrow = lgrp*4+r (replicated over lgrp)
    unsigned short* op = ctx + (size_t)(b * S + q0 + wq * 32) * D + h * 64;
#pragma unroll
    for (int qb = 0; qb < 2; ++qb)
#pragma unroll
      for (int r = 0; r < 4; ++r) {
        float inv = 1.0f / __shfl(l[qb], lgrp * 4 + r, 64);
        int row = qb * 16 + lgrp * 4 + r;
#pragma unroll
        for (int hb = 0; hb < 4; ++hb)
          op[(size_t)row * D + hb * 16 + lrow] = f2bf(o[qb][hb][r] * inv);
      }
  }
}

// ---------------------------------- launch ----------------------------------
extern "C" void kernel_launch(void* const* d_in, const int* in_sizes, int n_in,
                              void* d_out, int out_size, void* d_ws, size_t ws_size,
                              hipStream_t stream) {
  const float* x       = (const float*)d_in[0];   // [2,2048,1024] fp32
  const float* W_qkv   = (const float*)d_in[1];   // [1024,3072] fp32
  const float* q_scale = (const float*)d_in[2];   // [1024] fp32
  const float* k_scale = (const float*)d_in[3];   // [1024] fp32
  const float* W_out   = (const float*)d_in[4];   // [1024,1024] fp32
  float* out = (float*)d_out;                     // [2,2048,1024] fp32
  char* ws = (char*)d_ws;
  unsigned short* WT_qkv = (unsigned short*)(ws + 0);         //  6291456
  unsigned short* WT_out = (unsigned short*)(ws + 6291456);   //  2097152
  unsigned short* qkv    = (unsigned short*)(ws + 8388608);   // 25165824
  unsigned short* q_nb   = (unsigned short*)(ws + 33554432);  //  8388608
  unsigned short* k_nb   = (unsigned short*)(ws + 41943040);  //  8388608
  unsigned short* VT     = (unsigned short*)(ws + 50331648);  //  8388608
  unsigned short* x_bf   = (unsigned short*)(ws + 58720256);  //  8388608 -> 64 MiB
  unsigned short* ctx    = qkv;  // alias: qkv dead after k_lnv

  k_prep<<<8192, 256, 0, stream>>>(x, W_qkv, W_out, x_bf, WT_qkv, WT_out);
  k_gemm_bt<128, false><<<dim3(32, 24), 256, 0, stream>>>(x_bf, WT_qkv, qkv, 4096, 3072, 1024);
  k_lnv<<<8192, 256, 0, stream>>>(qkv, q_scale, k_scale, q_nb, k_nb, VT);
  k_flash<<<dim3(32, 32), 256, 0, stream>>>(q_nb, k_nb, VT, ctx);
  k_gemm_bt<64, true><<<dim3(64, 8), 256, 0, stream>>>(ctx, WT_out, out, 4096, 1024, 1024);
}